// Round 1
// 200.299 us; speedup vs baseline: 1.0082x; 1.0082x over previous
//
#include <hip/hip_runtime.h>

// CountHistogram: B=64, C=4, Q=32, D=4096, NBINS=29
// out[b,c,q,bin] = sum_d mask[b,q,d] * (bin == trunc((simmat[b,c,q,d]+1.00001)/2*28))
//
// R6: occupancy/residency round. Evidence: R0 (serialized atomics), R2
// (conflict-free atomics) and R5 (no atomics) all within ~1.5us -> LDS was
// never the limiter; kernel (~46us = dur 202 - 2x78us poison fills) sits at
// ~3.6 TB/s, 58% of achievable HBM read BW, while VALU/LDS pipe budgets are
// ~4-10us. Theory: latency-hiding shortfall from residency caps:
//   - LDS 29,696 B/block -> only 5 of 8 assigned blocks/CU resident (5+3 tail)
//   - unroll-8 VGPR pressure (~16 hoisted dwordx4) -> ~5-6 waves/SIMD anyway
// Fix: pack 2 bins per u32 as u16 halves (per-lane-column count <= 64, no
// overflow, no cross-half carry) -> LDS 15,360 B/block; __launch_bounds__
// (256,8) + unroll 4 to fit 64 VGPR -> 8 waves/SIMD; all 8 blocks/CU
// resident, zero tail. Same MLP/SIMD as before (4 loads x 8 waves vs
// 8 x 4), double the stall absorbers. Epilogue: 2 lanes per bin (column
// halves 0-31 / 32-63), bank-rotated b32 reads (2-way free tier), one
// __shfl_down(32) combine -> 33 LDS instrs vs 64.
// Kept from R3/R4/R5: nontemporal simmat stream, cached mask (shared by the
// 4 waves of a block via L1), non-atomic per-lane-column privatized RMW
// (lane owns column `lane`; bank = lane&31 -> 2 lanes/bank on distinct
// dwords = free tier, m136).

constexpr int Bdim  = 64;
constexpr int Cdim  = 4;
constexpr int Qdim  = 32;
constexpr int Ddim  = 4096;
constexpr int NBINS = 29;
constexpr int NROWS = (NBINS + 1) / 2;    // 15 word-rows, 2 bins packed per u32
constexpr int NCOPY = 64;                 // one private column per lane
constexpr int WHIST = NROWS * NCOPY;      // 960 words per wave

typedef float vf4 __attribute__((ext_vector_type(4)));
typedef int   vi4 __attribute__((ext_vector_type(4)));

__global__ __launch_bounds__(256, 8) void CountHistogram_33809982554604_kernel(
    const float* __restrict__ simmat,   // [B,C,Q,D] f32
    const int*   __restrict__ mask,     // [B,Q,D]   int32 (0/1)
    float*       __restrict__ out)      // [B,C,Q,NBINS] f32
{
    __shared__ unsigned int hist[4][WHIST];   // 15,360 B total -> 8 blocks/CU

    const int bq   = blockIdx.x;          // 0 .. B*Q-1
    const int b    = bq >> 5;             // Q = 32
    const int q    = bq & 31;
    const int wave = threadIdx.x >> 6;    // = c
    const int lane = threadIdx.x & 63;

    unsigned int* __restrict__ h = hist[wave];

    // zero this wave's private columns (wave-private: lockstep, no barrier)
    #pragma unroll
    for (int i = lane; i < WHIST; i += 64) h[i] = 0u;   // 15 iters

    const float* __restrict__ srow =
        simmat + (((size_t)b * Cdim + wave) * Qdim + q) * Ddim;
    const int* __restrict__ mrow =
        mask + ((size_t)b * Qdim + q) * Ddim;

    #pragma unroll 4
    for (int j = 0; j < Ddim / 256; ++j) {      // 16 iterations
        const int idx = (j * 64 + lane) * 4;    // element index of this lane's float4
        // simmat: read-once stream -> nontemporal
        const vf4 x = __builtin_nontemporal_load(
            reinterpret_cast<const vf4*>(srow + idx));
        // mask: reused by all 4 waves of this block -> normal cached load
        const vi4 m = *reinterpret_cast<const vi4*>(mrow + idx);

        // (x+1.00001f)*14.0f is bit-identical to ((x+1.00001)/2)*28:
        // /2 is exact, single rounding on the *14 either way.
        int b0 = (int)((x.x + 1.00001f) * 14.0f);
        int b1 = (int)((x.y + 1.00001f) * 14.0f);
        int b2 = (int)((x.z + 1.00001f) * 14.0f);
        int b3 = (int)((x.w + 1.00001f) * 14.0f);
        b0 = min(b0, NBINS - 1);
        b1 = min(b1, NBINS - 1);
        b2 = min(b2, NBINS - 1);
        b3 = min(b3, NBINS - 1);

        // packed u16 RMW: word = bin>>1, halfword = bin&1; lane owns column
        // `lane` -> no aliasing within the wave, program-ordered per lane.
        h[(b0 >> 1) * NCOPY + lane] += (unsigned int)m.x << ((b0 & 1) << 4);
        h[(b1 >> 1) * NCOPY + lane] += (unsigned int)m.y << ((b1 & 1) << 4);
        h[(b2 >> 1) * NCOPY + lane] += (unsigned int)m.z << ((b2 & 1) << 4);
        h[(b3 >> 1) * NCOPY + lane] += (unsigned int)m.w << ((b3 & 1) << 4);
    }

    // compiler fence: LDS writes above complete (in wave-order) before the
    // cross-lane reads below; lanes of one wave run in lockstep, no s_barrier.
    __builtin_amdgcn_wave_barrier();

    // Epilogue: 2 lanes per bin. Lane l (l&31 = bin) sums column half
    // cb = (l>=32)*32; rotation (i+lane)&31 keeps lanes on distinct banks
    // (word%32 = col%32 since row stride 64 == 0 mod 32) -> 2-way free tier.
    const int bin = lane & 31;
    unsigned int sum = 0u;
    if (bin < NBINS) {
        const int w  = bin >> 1;
        const int sh = (bin & 1) << 4;
        const int cb = (lane >> 5) << 5;    // 0 or 32
        const unsigned int* __restrict__ hr = h + w * NCOPY + cb;
        #pragma unroll
        for (int i = 0; i < 32; ++i) {
            const int c = (i + lane) & 31;
            sum += (hr[c] >> sh) & 0xffffu;
        }
    }
    // combine column halves: lane l (<29) += lane l+32's partial
    const unsigned int other = (unsigned int)__shfl_down((int)sum, 32, 64);
    if (lane < NBINS) {
        out[(((size_t)b * Cdim + wave) * Qdim + q) * NBINS + lane] =
            (float)(sum + other);
    }
}

extern "C" void kernel_launch(void* const* d_in, const int* in_sizes, int n_in,
                              void* d_out, int out_size, void* d_ws, size_t ws_size,
                              hipStream_t stream) {
    const float* simmat = (const float*)d_in[0];
    const int*   mask   = (const int*)d_in[1];
    float*       out    = (float*)d_out;

    dim3 grid(Bdim * Qdim);   // 2048 blocks: one per (b,q)
    dim3 block(256);          // 4 waves: one per c
    CountHistogram_33809982554604_kernel<<<grid, block, 0, stream>>>(simmat, mask, out);
}